// Round 7
// baseline (241.529 us; speedup 1.0000x reference)
//
#include <hip/hip_runtime.h>
#include <math.h>

#define B_  2
#define S_  2048
#define D_  1024
#define H_  16
#define HD_ 64
#define BS_ (B_ * S_)   // 4096 rows

typedef __bf16 bf16_t;
typedef __bf16 bf16x8 __attribute__((ext_vector_type(8)));
typedef __bf16 bf16x4 __attribute__((ext_vector_type(4)));
typedef float  f32x4  __attribute__((ext_vector_type(4)));

#define QSCALE 0.18033688011112042f   // 0.125 * log2(e)
#define FREQC  0.28782313662425575f   // ln(10000)/32

// Async global->LDS DMA, 16 B per lane (wave-uniform LDS base + lane*16).
__device__ __forceinline__ void async_ld16(const bf16_t* g, bf16_t* l)
{
    __builtin_amdgcn_global_load_lds(
        (const __attribute__((address_space(1))) void*)g,
        (__attribute__((address_space(3))) void*)l,
        16, 0, 0);
}

// ---------------------------------------------------------------------------
// Weight fp32 -> bf16 convert (both weight matrices, one kernel).
// ---------------------------------------------------------------------------
__global__ __launch_bounds__(256) void cvt_w(const float* __restrict__ a,
                                             const float* __restrict__ b,
                                             bf16_t* __restrict__ oa,
                                             bf16_t* __restrict__ ob)
{
    int idx = blockIdx.x * 256 + threadIdx.x;
    const int NA = 3 * D_ * D_ / 4;   // 786432 float4 chunks in qkv_w
    if (idx < NA) {
        float4 v = ((const float4*)a)[idx];
        bf16x4 p;
        p[0] = (bf16_t)v.x; p[1] = (bf16_t)v.y; p[2] = (bf16_t)v.z; p[3] = (bf16_t)v.w;
        ((bf16x4*)oa)[idx] = p;
    } else {
        int j = idx - NA;
        float4 v = ((const float4*)b)[j];
        bf16x4 p;
        p[0] = (bf16_t)v.x; p[1] = (bf16_t)v.y; p[2] = (bf16_t)v.z; p[3] = (bf16_t)v.w;
        ((bf16x4*)ob)[j] = p;
    }
}

// ---------------------------------------------------------------------------
// LayerNorm: one block per row of 1024 floats; bf16 output.
// ---------------------------------------------------------------------------
__global__ __launch_bounds__(256) void ln_kernel(const float* __restrict__ x,
                                                 const float* __restrict__ gamma,
                                                 const float* __restrict__ beta,
                                                 bf16_t* __restrict__ y)
{
    int row = blockIdx.x;
    float4 v = ((const float4*)(x + (size_t)row * D_))[threadIdx.x];
    float sum = v.x + v.y + v.z + v.w;
    float sq  = v.x * v.x + v.y * v.y + v.z * v.z + v.w * v.w;
#pragma unroll
    for (int off = 32; off > 0; off >>= 1) {
        sum += __shfl_down(sum, off);
        sq  += __shfl_down(sq, off);
    }
    __shared__ float s_sum[4], s_sq[4];
    int wave = threadIdx.x >> 6;
    if ((threadIdx.x & 63) == 0) { s_sum[wave] = sum; s_sq[wave] = sq; }
    __syncthreads();
    float tsum = s_sum[0] + s_sum[1] + s_sum[2] + s_sum[3];
    float tsq  = s_sq[0] + s_sq[1] + s_sq[2] + s_sq[3];
    float mean = tsum * (1.0f / D_);
    float var  = tsq * (1.0f / D_) - mean * mean;
    float rstd = rsqrtf(var + 1e-5f);
    float4 g = ((const float4*)gamma)[threadIdx.x];
    float4 b = ((const float4*)beta)[threadIdx.x];
    bf16x4 o;
    o[0] = (bf16_t)((v.x - mean) * rstd * g.x + b.x);
    o[1] = (bf16_t)((v.y - mean) * rstd * g.y + b.y);
    o[2] = (bf16_t)((v.z - mean) * rstd * g.z + b.z);
    o[3] = (bf16_t)((v.w - mean) * rstd * g.w + b.w);
    *(bf16x4*)&y[(size_t)row * D_ + threadIdx.x * 4] = o;
}

// ---------------------------------------------------------------------------
// bf16 MFMA GEMM: C = A[M][K] * W[N][K]^T + bias.
// 128x128 tile, BK=32, 4 waves (64x64 quadrant each).
// Staging: global_load_lds w=16, double-buffered, ONE barrier per K-iter.
// XOR chunk swizzle: LDS slot s of row r holds global chunk s^(r&3).
// MODE 0: fp32 output (proj). MODE 1: fused rope + scatter to
//   q[b][h][s][hd] (scaled), k[b][h][s][hd], v^T[b][h][hd][s], all bf16.
// ---------------------------------------------------------------------------
template<int MODE>
__global__ __launch_bounds__(256) void gemm_bf16(const bf16_t* __restrict__ A,
                                                 const bf16_t* __restrict__ W,
                                                 const float* __restrict__ bias,
                                                 float* __restrict__ outf,
                                                 bf16_t* __restrict__ qout,
                                                 bf16_t* __restrict__ kout,
                                                 bf16_t* __restrict__ vout,
                                                 int M, int N, int K)
{
    constexpr int SMEM = (MODE == 1) ? 18432 : 16384;
    __shared__ bf16_t smem[SMEM];
    const int bm = blockIdx.y * 128, bn = blockIdx.x * 128;
    const int tid = threadIdx.x;
    const int wave = tid >> 6, lane = tid & 63;
    const int ln16 = lane & 15, quad = lane >> 4;
    const int wr = (wave >> 1) * 64, wc = (wave & 1) * 64;
    const int slot_a = (quad ^ (ln16 & 3)) * 8;

    f32x4 acc[4][4];
#pragma unroll
    for (int i = 0; i < 4; i++)
#pragma unroll
        for (int j = 0; j < 4; j++) acc[i][j] = (f32x4){0.f, 0.f, 0.f, 0.f};

#pragma unroll
    for (int j = 0; j < 2; j++) {
        int e = j * 256 + tid;
        int r = e >> 2, cg = ((e & 3) ^ (r & 3)) * 8;
        async_ld16(&A[(size_t)(bm + r) * K + cg], smem + e * 8);
        async_ld16(&W[(size_t)(bn + r) * K + cg], smem + 4096 + e * 8);
    }
    __syncthreads();

    for (int k0 = 0, it = 0; k0 < K; k0 += 32, it++) {
        const bf16_t* cur = smem + (it & 1) * 8192;
        bf16_t* nxt = smem + ((it & 1) ^ 1) * 8192;
        if (k0 + 32 < K) {
#pragma unroll
            for (int j = 0; j < 2; j++) {
                int e = j * 256 + tid;
                int r = e >> 2, cg = ((e & 3) ^ (r & 3)) * 8;
                async_ld16(&A[(size_t)(bm + r) * K + k0 + 32 + cg], nxt + e * 8);
                async_ld16(&W[(size_t)(bn + r) * K + k0 + 32 + cg], nxt + 4096 + e * 8);
            }
        }

        bf16x8 af[4], bf[4];
#pragma unroll
        for (int mi = 0; mi < 4; mi++)
            af[mi] = *(const bf16x8*)&cur[(wr + mi * 16 + ln16) * 32 + slot_a];
#pragma unroll
        for (int ni = 0; ni < 4; ni++)
            bf[ni] = *(const bf16x8*)&cur[4096 + (wc + ni * 16 + ln16) * 32 + slot_a];
#pragma unroll
        for (int mi = 0; mi < 4; mi++)
#pragma unroll
            for (int ni = 0; ni < 4; ni++)
                acc[mi][ni] = __builtin_amdgcn_mfma_f32_16x16x32_bf16(
                    af[mi], bf[ni], acc[mi][ni], 0, 0, 0);

        __syncthreads();
    }

#pragma unroll
    for (int ni = 0; ni < 4; ni++) {
        float bb = bias[bn + wc + ni * 16 + ln16];
#pragma unroll
        for (int mi = 0; mi < 4; mi++)
#pragma unroll
            for (int r = 0; r < 4; r++) acc[mi][ni][r] += bb;
    }

    if (MODE == 0) {
#pragma unroll
        for (int ni = 0; ni < 4; ni++) {
            int n = bn + wc + ni * 16 + ln16;
#pragma unroll
            for (int mi = 0; mi < 4; mi++)
#pragma unroll
                for (int r = 0; r < 4; r++)
                    outf[(size_t)(bm + wr + mi * 16 + quad * 4 + r) * N + n] = acc[mi][ni][r];
        }
    } else {
        const int n64 = (bn + wc) >> 6;
        const int t = n64 % 3, h = n64 / 3;
        if (t == 2) {
#pragma unroll
            for (int mi = 0; mi < 4; mi++) {
                int m0 = bm + wr + mi * 16 + quad * 4;
                int b = m0 >> 11, s0 = m0 & (S_ - 1);
#pragma unroll
                for (int ni = 0; ni < 4; ni++) {
                    int hd = ni * 16 + ln16;
                    bf16x4 pk;
#pragma unroll
                    for (int r = 0; r < 4; r++) pk[r] = (bf16_t)acc[mi][ni][r];
                    *(bf16x4*)&vout[((size_t)(b * H_ + h) * HD_ + hd) * S_ + s0] = pk;
                }
            }
        } else {
            bf16_t* T = smem + wave * (64 * 72);
            float fr0 = __expf(-(float)ln16 * FREQC);
            float fr1 = __expf(-(float)(16 + ln16) * FREQC);
            float sc = (t == 0) ? QSCALE : 1.0f;
#pragma unroll
            for (int mi = 0; mi < 4; mi++) {
#pragma unroll
                for (int r = 0; r < 4; r++) {
                    int m = bm + wr + mi * 16 + quad * 4 + r;
                    float s = (float)(m & (S_ - 1));
                    float sn0, cs0, sn1, cs1;
                    __sincosf(s * fr0, &sn0, &cs0);
                    __sincosf(s * fr1, &sn1, &cs1);
                    int rowo = (mi * 16 + quad * 4 + r) * 72;
                    float x1 = acc[mi][0][r], x2 = acc[mi][2][r];
                    T[rowo + ln16]      = (bf16_t)((x1 * cs0 - x2 * sn0) * sc);
                    T[rowo + 32 + ln16] = (bf16_t)((x2 * cs0 + x1 * sn0) * sc);
                    x1 = acc[mi][1][r]; x2 = acc[mi][3][r];
                    T[rowo + 16 + ln16] = (bf16_t)((x1 * cs1 - x2 * sn1) * sc);
                    T[rowo + 48 + ln16] = (bf16_t)((x2 * cs1 + x1 * sn1) * sc);
                }
            }
            bf16_t* dst = (t == 0) ? qout : kout;
#pragma unroll
            for (int e = lane; e < 512; e += 64) {
                int row_l = e >> 3, c8 = (e & 7) << 3;
                int m = bm + wr + row_l;
                int b = m >> 11, s = m & (S_ - 1);
                *(bf16x8*)&dst[((size_t)(b * H_ + h) * S_ + s) * HD_ + c8] =
                    *(const bf16x8*)&T[row_l * 72 + c8];
            }
        }
    }
}

// ---------------------------------------------------------------------------
// Flash attention v5. Block = 128 q (4 waves x 32 q), grid (16,16,2).
// K (64x64) and V^T (64x64) single-buffered in LDS via global_load_lds
// (XOR-8 chunk swizzle), 2 barriers per kt. 32 q per wave (nq=2 strips)
// amortizes softmax/barrier/P-trip fixed costs over 32 MFMAs per iter.
// LDS 34.8 KB -> 4 blocks/CU.
// ---------------------------------------------------------------------------
__global__ __launch_bounds__(256, 4) void attn_fa(const bf16_t* __restrict__ q_buf,
                                                  const bf16_t* __restrict__ k_buf,
                                                  const bf16_t* __restrict__ v_t,
                                                  bf16_t* __restrict__ ctx)
{
    __shared__ bf16_t Ks[4096];
    __shared__ bf16_t Vt[4096];
    __shared__ bf16_t P_lds[4][32 * 72];

    const int bx = blockIdx.x, h = blockIdx.y, b = blockIdx.z;
    const int qt = (bx & 1) ? (bx >> 1) : (15 - (bx >> 1));  // heavy tiles first
    const int tid = threadIdx.x;
    const int wave = tid >> 6, lane = tid & 63;
    const int ln16 = lane & 15, quad = lane >> 4;
    const int w0 = qt * 128 + wave * 32;
    const int s7 = ln16 & 7;

    const bf16_t* qb = q_buf + (size_t)(b * H_ + h) * S_ * HD_;
    const bf16_t* kb = k_buf + (size_t)(b * H_ + h) * S_ * HD_;
    const bf16_t* vb = v_t  + (size_t)(b * H_ + h) * HD_ * S_;
    bf16_t* Pw = &P_lds[wave][0];

    // Q B-frags (regs, whole kernel): B[k=hd][n=q=ln16], two 16-q strips
    bf16x8 qf[2][2];
#pragma unroll
    for (int nq = 0; nq < 2; nq++)
#pragma unroll
        for (int kc = 0; kc < 2; kc++)
            qf[nq][kc] = *(const bf16x8*)&qb[(size_t)(w0 + nq * 16 + ln16) * HD_ + kc * 32 + quad * 8];

    f32x4 o[2][4];
#pragma unroll
    for (int nq = 0; nq < 2; nq++)
#pragma unroll
        for (int mi = 0; mi < 4; mi++) o[nq][mi] = (f32x4){0.f, 0.f, 0.f, 0.f};
    float m_i[2] = {-1e30f, -1e30f}, l_i[2] = {0.f, 0.f};

    const int my_ktmax  = (w0 + 31) >> 6;   // last tile this wave needs
    const int blk_ktmax = 2 * qt + 1;       // last tile any wave in block needs

    for (int kt = 0; kt <= blk_ktmax; kt++) {
        __syncthreads();   // all waves done reading previous tile
#pragma unroll
        for (int j = 0; j < 2; j++) {
            int e = j * 256 + tid;               // 0..511
            int r = e >> 3, cg = ((e & 7) ^ (r & 7)) * 8;
            async_ld16(&kb[(size_t)(kt * 64 + r) * HD_ + cg], &Ks[e * 8]);
            async_ld16(&vb[(size_t)r * S_ + kt * 64 + cg],    &Vt[e * 8]);
        }
        __syncthreads();   // tile visible (vmcnt drained by barrier)
        if (kt > my_ktmax) continue;   // wave done; still hits barriers above

        // S^T = K Q^T : 64 keys x 32 q (two 16-q strips)
        f32x4 st[2][4];
#pragma unroll
        for (int nq = 0; nq < 2; nq++)
#pragma unroll
            for (int cb = 0; cb < 4; cb++) st[nq][cb] = (f32x4){0.f, 0.f, 0.f, 0.f};
#pragma unroll
        for (int kc = 0; kc < 2; kc++) {
#pragma unroll
            for (int cb = 0; cb < 4; cb++) {
                bf16x8 kf = *(const bf16x8*)&Ks[(cb * 16 + ln16) * 64 + ((kc * 4 + quad) ^ s7) * 8];
                st[0][cb] = __builtin_amdgcn_mfma_f32_16x16x32_bf16(kf, qf[0][kc], st[0][cb], 0, 0, 0);
                st[1][cb] = __builtin_amdgcn_mfma_f32_16x16x32_bf16(kf, qf[1][kc], st[1][cb], 0, 0, 0);
            }
        }

        if (kt == my_ktmax) {   // causal: key = kt*64+cb*16+quad*4+r, q = w0+nq*16+ln16
#pragma unroll
            for (int nq = 0; nq < 2; nq++) {
                int q_g = w0 + nq * 16 + ln16;
#pragma unroll
                for (int cb = 0; cb < 4; cb++) {
                    int key0 = kt * 64 + cb * 16 + quad * 4;
#pragma unroll
                    for (int r = 0; r < 4; r++)
                        if (key0 + r > q_g) st[nq][cb][r] = -1e30f;
                }
            }
        }

        // online softmax (log2 units), per 16-q strip
#pragma unroll
        for (int nq = 0; nq < 2; nq++) {
            float mx = st[nq][0][0];
#pragma unroll
            for (int cb = 0; cb < 4; cb++)
#pragma unroll
                for (int r = 0; r < 4; r++) mx = fmaxf(mx, st[nq][cb][r]);
            mx = fmaxf(mx, __shfl_xor(mx, 16));
            mx = fmaxf(mx, __shfl_xor(mx, 32));
            float mn = fmaxf(m_i[nq], mx);
            float sum = 0.f;
#pragma unroll
            for (int cb = 0; cb < 4; cb++)
#pragma unroll
                for (int r = 0; r < 4; r++) {
                    float p = exp2f(st[nq][cb][r] - mn);
                    st[nq][cb][r] = p;
                    sum += p;
                }
            sum += __shfl_xor(sum, 16);
            sum += __shfl_xor(sum, 32);
            float al = exp2f(m_i[nq] - mn);
            l_i[nq] = l_i[nq] * al + sum;
            m_i[nq] = mn;
#pragma unroll
            for (int mi = 0; mi < 4; mi++) {
                o[nq][mi][0] *= al; o[nq][mi][1] *= al;
                o[nq][mi][2] *= al; o[nq][mi][3] *= al;
            }
#pragma unroll
            for (int cb = 0; cb < 4; cb++) {
                bf16x4 pk;
#pragma unroll
                for (int r = 0; r < 4; r++) pk[r] = (bf16_t)st[nq][cb][r];
                *(bf16x4*)&Pw[(nq * 16 + ln16) * 72 + cb * 16 + quad * 4] = pk;
            }
        }

        // O^T += V^T P^T
#pragma unroll
        for (int kc = 0; kc < 2; kc++) {
            bf16x8 pf0 = *(const bf16x8*)&Pw[ln16 * 72 + kc * 32 + quad * 8];
            bf16x8 pf1 = *(const bf16x8*)&Pw[(16 + ln16) * 72 + kc * 32 + quad * 8];
#pragma unroll
            for (int mi = 0; mi < 4; mi++) {
                bf16x8 vf = *(const bf16x8*)&Vt[(mi * 16 + ln16) * 64 + ((kc * 4 + quad) ^ s7) * 8];
                o[0][mi] = __builtin_amdgcn_mfma_f32_16x16x32_bf16(vf, pf0, o[0][mi], 0, 0, 0);
                o[1][mi] = __builtin_amdgcn_mfma_f32_16x16x32_bf16(vf, pf1, o[1][mi], 0, 0, 0);
            }
        }
    }

    // write ctx[b][s][h*64+hd] bf16; O^T C-layout: col q=ln16, rows hd
#pragma unroll
    for (int nq = 0; nq < 2; nq++) {
        float inv = 1.0f / l_i[nq];
        int s = w0 + nq * 16 + ln16;
#pragma unroll
        for (int mi = 0; mi < 4; mi++) {
            bf16x4 pk;
#pragma unroll
            for (int r = 0; r < 4; r++) pk[r] = (bf16_t)(o[nq][mi][r] * inv);
            *(bf16x4*)&ctx[(size_t)(b * S_ + s) * D_ + h * HD_ + mi * 16 + quad * 4] = pk;
        }
    }
}

// ---------------------------------------------------------------------------
extern "C" void kernel_launch(void* const* d_in, const int* in_sizes, int n_in,
                              void* d_out, int out_size, void* d_ws, size_t ws_size,
                              hipStream_t stream)
{
    const float* hidden = (const float*)d_in[0];
    const float* gamma  = (const float*)d_in[1];
    const float* beta   = (const float*)d_in[2];
    const float* qkv_w  = (const float*)d_in[3];
    const float* qkv_b  = (const float*)d_in[4];
    const float* proj_w = (const float*)d_in[5];
    const float* proj_b = (const float*)d_in[6];
    float* out = (float*)d_out;

    char* ws = (char*)d_ws;
    const size_t MB = 1024 * 1024;
    bf16_t* x_ln = (bf16_t*)(ws);             //  0.. 8 MB
    bf16_t* wq   = (bf16_t*)(ws +  8 * MB);   //  8..14 MB
    bf16_t* wp   = (bf16_t*)(ws + 14 * MB);   // 14..16 MB
    bf16_t* qbf  = (bf16_t*)(ws + 16 * MB);   // 16..24 MB
    bf16_t* kbf  = (bf16_t*)(ws + 24 * MB);   // 24..32 MB
    bf16_t* vtb  = (bf16_t*)(ws + 32 * MB);   // 32..40 MB
    bf16_t* ctx  = (bf16_t*)(ws + 40 * MB);   // 40..48 MB

    cvt_w<<<4096, 256, 0, stream>>>(qkv_w, proj_w, wq, wp);
    ln_kernel<<<BS_, 256, 0, stream>>>(hidden, gamma, beta, x_ln);
    gemm_bf16<1><<<dim3(24, 32), 256, 0, stream>>>(
        x_ln, wq, qkv_b, nullptr, qbf, kbf, vtb, BS_, 3 * D_, D_);
    attn_fa<<<dim3(16, H_, B_), 256, 0, stream>>>(qbf, kbf, vtb, ctx);
    gemm_bf16<0><<<dim3(8, 32), 256, 0, stream>>>(
        ctx, wp, proj_b, out, nullptr, nullptr, nullptr, BS_, D_, D_);
}